// Round 23
// baseline (432.083 us; speedup 1.0000x reference)
//
#include <hip/hip_runtime.h>
#include <hip/hip_bf16.h>

typedef __attribute__((ext_vector_type(8))) short short8;
typedef __attribute__((ext_vector_type(4))) float f32x4;
typedef __attribute__((ext_vector_type(2))) float f32x2;

#define B_T 200
#define B_D 128

typedef const __attribute__((address_space(1))) void gvoid;
typedef __attribute__((address_space(3))) void lvoid;

static __device__ __forceinline__ short f2bf(float f) {
  // round-to-nearest-even f32 -> bf16 (inputs are finite)
  unsigned u = __builtin_bit_cast(unsigned, f);
  u += 0x7fffu + ((u >> 16) & 1u);
  return (short)(u >> 16);
}
static __device__ __forceinline__ short8 cvt8(f32x4 a, f32x4 b) {
  short8 t;
  t[0] = f2bf(a[0]); t[1] = f2bf(a[1]); t[2] = f2bf(a[2]); t[3] = f2bf(a[3]);
  t[4] = f2bf(b[0]); t[5] = f2bf(b[1]); t[6] = f2bf(b[2]); t[7] = f2bf(b[3]);
  return t;
}

// 512 threads / 8 waves, FLAT __launch_bounds__(512): natural allocation.
// Demand ~50 regs (Bf=16, no staging regs via global_load_lds) -> expect
// ~48-64 VGPR, no spill, and HW residency up to 4 blocks = 32 waves/CU.
// [R19 identical structure spilled ONLY because (512,8) budgeted 32 regs.]
__global__ __launch_bounds__(512)
void ta_fused(const float* __restrict__ x,      // [B,T,D]
              const float* __restrict__ cand,   // [B,D]
              const void*  __restrict__ maskp,  // [B,T] int32 or 1-byte bool
              const float* __restrict__ W1,     // [384,128]
              const float* __restrict__ b1,     // [128]
              const float* __restrict__ ap,     // [1]
              const float* __restrict__ W2,     // [128]
              const float* __restrict__ b2p,    // [1] (unused: softmax shift-invariant)
              float* __restrict__ out)          // [B,D]
{
  // a_lds: two f32 x-tiles [16][128]. global_load_lds writes LINEAR
  // (base + lane*16); the bank-swizzle is applied on the GLOBAL SOURCE
  // address (unit u of row r holds global unit u^(r&7)) and undone on read.
  __shared__ __align__(16) float a_lds[2][16 * B_D];   // 16 KB
  __shared__ __align__(16) float smem2[8 * 208 + 208]; // sp[8][208] | scores[208]
  __shared__ float red[16];
  float (*sp)[208] = (float (*)[208])smem2;
  float* scores = smem2 + 8 * 208;
  float (*part)[B_D] = (float (*)[B_D])smem2;          // aliases sp (phase C)

  const int b    = blockIdx.x;
  const int tid  = threadIdx.x;
  const int lane = tid & 63;
  const int wv   = tid >> 6;      // 0..7
  const int l15  = lane & 15;
  const int g    = lane >> 4;     // 0..3

  // ---- mask dtype probe (same 512B on every wave -> block-consistent)
  int flag1b;
  {
    const unsigned char* mb = (const unsigned char*)maskp;
    unsigned long long v8 = *(const unsigned long long*)(mb + lane * 8);
    flag1b = __any((v8 & 0xFFFFFF00FFFFFF00ull) != 0ull);
  }
  bool mk = false;
  if (tid < B_T) {
    if (flag1b) mk = ((const unsigned char*)maskp)[(size_t)b * B_T + tid] != 0;
    else        mk = ((const int*)maskp)[(size_t)b * B_T + tid] != 0;
  }

  // ---- STAGE: wave wv moves its 1 KB strip of tile MT (f32, 8 KB total).
  // 16B-unit index off16 = wv*64+lane; r = off16>>5, u = off16&31.
  // LDS linear (base wv*1024 + lane*16); global source pre-swizzled u^(r&7).
  // Tile 12 (rows 192..199): only waves 0..3 (r<8); rows 8..15 stay stale
  // (finite, from tile 10) and are masked in softmax (t>=200).
#define STAGE(MT, BUF) do {                                                   \
    if ((MT) < 12 || wv < 4) {                                                \
      const int off16_ = wv * 64 + lane;                                      \
      const int r_ = off16_ >> 5, u_ = off16_ & 31;                           \
      const float* gp_ = x + ((size_t)b * B_T + (MT) * 16 + r_) * B_D         \
                           + ((u_ ^ (r_ & 7)) << 2);                          \
      __builtin_amdgcn_global_load_lds((gvoid*)gp_,                           \
          (lvoid*)&a_lds[BUF][wv * 256], 16, 0, 0);                           \
    }                                                                         \
  } while (0)

  STAGE(0, 0);
  STAGE(1, 1);

  // ---- phase 1 (register-resident): B-frags + beta for column j0 = wv*16+l15
  const float* cb = cand + (size_t)b * B_D;
  const int j0 = wv * 16 + l15;
  short8 Bf[4];
  #pragma unroll
  for (int ks = 0; ks < 4; ++ks) {
    short8 t;
    #pragma unroll
    for (int e = 0; e < 8; ++e) {
      const int k = ks * 32 + g * 8 + e;
      t[e] = f2bf(fmaf(cb[k], W1[(size_t)(256 + k) * B_D + j0],
                       W1[(size_t)k * B_D + j0]));
    }
    Bf[ks] = t;
  }
  float beta;
  {
    float s = 0.f;
    #pragma unroll 8
    for (int kk = 0; kk < 32; ++kk) {
      const int k = g * 32 + kk;
      s = fmaf(cb[k], W1[(size_t)(B_D + k) * B_D + j0], s);
    }
    s += __shfl_xor(s, 16, 64); s += __shfl_xor(s, 32, 64);
    beta = s + b1[j0];
  }
  const float w2v  = W2[j0];
  const float alpha = ap[0];
  __syncthreads();   // drains global_load_lds: tiles 0,1 ready

  // ---- phase A: 13 tiles, double-buffered; stage mt+2 right after the
  // barrier that frees its buffer. One barrier per tile.
  const int sw = l15 & 7;
  for (int mt = 0; mt < 13; ++mt) {
    const int buf = mt & 1;
    f32x4 acc = {0.f, 0.f, 0.f, 0.f};
    #pragma unroll
    for (int ks = 0; ks < 4; ++ks) {
      const int U0 = ks * 8 + g * 2;
      f32x4 fa = *(const f32x4*)&a_lds[buf][l15 * B_D + (((U0    ) ^ sw) << 2)];
      f32x4 fb = *(const f32x4*)&a_lds[buf][l15 * B_D + (((U0 + 1) ^ sw) << 2)];
      short8 a = cvt8(fa, fb);
      acc = __builtin_amdgcn_mfma_f32_16x16x32_bf16(a, Bf[ks], acc, 0, 0, 0);
    }
    // epilogue: PReLU + W2 on this wave's 16 j's, reduce over l15
    #pragma unroll
    for (int r = 0; r < 4; ++r) {
      float h = acc[r] + beta; h = (h >= 0.f) ? h : alpha * h;
      float v = h * w2v;
      v += __shfl_xor(v, 1, 16); v += __shfl_xor(v, 2, 16);
      v += __shfl_xor(v, 4, 16); v += __shfl_xor(v, 8, 16);
      if (l15 == 0) sp[wv][mt * 16 + g * 4 + r] = v;   // C row = g*4+r
    }
    __syncthreads();              // all waves done with buf; mt+1 committed
    if (mt + 2 < 13) STAGE(mt + 2, buf);   // async into the freed buffer
  }
#undef STAGE

  // ---- phase B: sum the 8 wave partials, masked softmax; scores <- e.
  {
    float s = -INFINITY;
    if (tid < B_T && mk) {
      float t0 = 0.f;
      #pragma unroll
      for (int w = 0; w < 8; ++w) t0 += sp[w][tid];
      s = t0;
    }
    float v = s;
    #pragma unroll
    for (int m = 32; m >= 1; m >>= 1) v = fmaxf(v, __shfl_xor(v, m, 64));
    if (lane == 0) red[wv] = v;
    __syncthreads();
    float mx = -INFINITY;
    #pragma unroll
    for (int i = 0; i < 8; ++i) mx = fmaxf(mx, red[i]);
    float e = (tid < B_T && mk) ? __expf(s - mx) : 0.f;
    float sv = e;
    #pragma unroll
    for (int m = 32; m >= 1; m >>= 1) sv += __shfl_xor(sv, m, 64);
    if (lane == 0) red[8 + wv] = sv;
    if (tid < 208) scores[tid] = e;   // t in [200,208): e==0
    __syncthreads();                  // sp dead after this -> part alias OK
  }

  // ---- phase C: part[wv][:] = sum_{t in wv-slice} e[t]*x[t,:] (L2/L3-hot).
  {
    const int d2 = lane * 2;
    const float* xc = x + ((size_t)b * B_T + wv * 25) * B_D + d2;
    f32x2 acc0 = {0.f, 0.f}, acc1 = {0.f, 0.f};
    #pragma unroll
    for (int t = 0; t < 24; t += 2) {
      f32x2 xv0 = *(const f32x2*)(xc + (size_t)t * B_D);
      f32x2 xv1 = *(const f32x2*)(xc + (size_t)(t + 1) * B_D);
      float w0 = scores[wv * 25 + t];
      float w1 = scores[wv * 25 + t + 1];
      acc0[0] = fmaf(w0, xv0[0], acc0[0]); acc1[0] = fmaf(w1, xv1[0], acc1[0]);
      acc0[1] = fmaf(w0, xv0[1], acc0[1]); acc1[1] = fmaf(w1, xv1[1], acc1[1]);
    }
    {
      f32x2 xv = *(const f32x2*)(xc + (size_t)24 * B_D);
      float w = scores[wv * 25 + 24];
      acc0[0] = fmaf(w, xv[0], acc0[0]); acc0[1] = fmaf(w, xv[1], acc0[1]);
    }
    acc0[0] += acc1[0]; acc0[1] += acc1[1];
    *(f32x2*)&part[wv][d2] = acc0;
  }
  __syncthreads();
  if (tid < B_D) {
    float Z = 0.f;
    #pragma unroll
    for (int i = 0; i < 8; ++i) Z += red[8 + i];
    float s = 0.f;
    #pragma unroll
    for (int p = 0; p < 8; ++p) s += part[p][tid];
    out[(size_t)b * B_D + tid] = s / Z;
  }
}

extern "C" void kernel_launch(void* const* d_in, const int* in_sizes, int n_in,
                              void* d_out, int out_size, void* d_ws, size_t ws_size,
                              hipStream_t stream) {
  const float* x    = (const float*)d_in[0];
  const float* cand = (const float*)d_in[1];
  const void*  mask = d_in[2];
  const float* W1   = (const float*)d_in[3];
  const float* b1   = (const float*)d_in[4];
  const float* a    = (const float*)d_in[5];
  const float* W2   = (const float*)d_in[6];
  const float* b2   = (const float*)d_in[7];
  float* out = (float*)d_out;
  const int B = in_sizes[1] / B_D;   // candidate is [B,128]
  ta_fused<<<B, 512, 0, stream>>>(x, cand, mask, W1, b1, a, W2, b2, out);
}